// Round 1
// baseline (1067.994 us; speedup 1.0000x reference)
//
#include <hip/hip_runtime.h>
#include <hip/hip_bf16.h>

// HRR self-attention, restructured to real arithmetic:
//   q = x@Wq^T; kv = x@Wkv^T           (bf16 MFMA GEMM)
//   q_hat = q/(sqrt(128)*||q||), per (b,s,h) head vector (Parseval folds fft-norm)
//   QF = q_hat @ CS^T   (real DFT-128 as GEMM; CS is 256x128: rows 0..127 cos, 128..255 -sin)
//   freq-domain causal cumsum of KF + complex multiply (chunked 2-pass scan)
//   V = QV @ W2^T       (iDFT real part as GEMM, 128x256)
//   out = V @ Wo^T      (fp32 out)

typedef unsigned short u16;
typedef __attribute__((ext_vector_type(8))) short short8;
typedef __attribute__((ext_vector_type(4))) float f32x4;

__device__ __forceinline__ float bf2f(u16 u) {
  unsigned int x = ((unsigned int)u) << 16;
  float f; __builtin_memcpy(&f, &x, 4); return f;
}
__device__ __forceinline__ u16 f2bf(float f) {
  __hip_bfloat16 h = __float2bfloat16(f);
  u16 u; __builtin_memcpy(&u, &h, 2); return u;
}

// ---------------- generic bf16 GEMM: C(MxN) = A(MxK) @ B(NxK)^T ----------------
// 128x128 block tile, BK=32, 256 threads = 4 waves (2x2 of 64x64), mfma 16x16x32.
template <bool OUT_BF16>
__global__ __launch_bounds__(256, 2) void gemm_bt(
    const u16* __restrict__ A, const u16* __restrict__ B, void* __restrict__ C,
    int M, int N, int K) {
  const int ntiles = N >> 7;
  const int bid = blockIdx.x;
  const int bm = bid / ntiles, bn = bid % ntiles;
  const long rowBase = (long)bm * 128, colBase = (long)bn * 128;

  __shared__ u16 As[128 * 40];  // pad stride 40 bf16 (80B) to break bank conflicts
  __shared__ u16 Bs[128 * 40];

  const int tid = threadIdx.x;
  const int wave = tid >> 6, lane = tid & 63;
  const int quad = lane >> 4, l16 = lane & 15;
  const int waveRow = (wave >> 1) * 64, waveCol = (wave & 1) * 64;

  const int r0 = tid >> 2;        // 0..63
  const int c0 = (tid & 3) * 8;   // 0,8,16,24

  f32x4 acc[4][4] = {};

  for (int kt = 0; kt < K; kt += 32) {
    const u16* ga = A + (rowBase + r0) * (long)K + kt + c0;
    short8 a0 = *(const short8*)ga;
    short8 a1 = *(const short8*)(ga + 64 * (long)K);
    const u16* gb = B + (colBase + r0) * (long)K + kt + c0;
    short8 b0 = *(const short8*)gb;
    short8 b1 = *(const short8*)(gb + 64 * (long)K);
    *(short8*)&As[r0 * 40 + c0] = a0;
    *(short8*)&As[(r0 + 64) * 40 + c0] = a1;
    *(short8*)&Bs[r0 * 40 + c0] = b0;
    *(short8*)&Bs[(r0 + 64) * 40 + c0] = b1;
    __syncthreads();

    short8 af[4], bfr[4];
#pragma unroll
    for (int i = 0; i < 4; i++)
      af[i] = *(const short8*)&As[(waveRow + i * 16 + l16) * 40 + quad * 8];
#pragma unroll
    for (int j = 0; j < 4; j++)
      bfr[j] = *(const short8*)&Bs[(waveCol + j * 16 + l16) * 40 + quad * 8];
#pragma unroll
    for (int i = 0; i < 4; i++)
#pragma unroll
      for (int j = 0; j < 4; j++)
        acc[i][j] = __builtin_amdgcn_mfma_f32_16x16x32_bf16(af[i], bfr[j], acc[i][j], 0, 0, 0);
    __syncthreads();
  }

  // C/D layout: col = lane&15, row = (lane>>4)*4 + reg  [verified m89/m91]
#pragma unroll
  for (int i = 0; i < 4; i++) {
#pragma unroll
    for (int j = 0; j < 4; j++) {
      long row0 = rowBase + waveRow + i * 16 + quad * 4;
      long col = colBase + waveCol + j * 16 + l16;
#pragma unroll
      for (int r = 0; r < 4; r++) {
        float v = acc[i][j][r];
        long off = (row0 + r) * (long)N + col;
        if (OUT_BF16) ((u16*)C)[off] = f2bf(v);
        else          ((float*)C)[off] = v;
      }
    }
  }
}

// ---------------- fp32 -> bf16 cast (vectorized x4) ----------------
__global__ __launch_bounds__(256) void cast_f2b(const float* __restrict__ in,
                                                u16* __restrict__ out, int n4) {
  int i = blockIdx.x * 256 + threadIdx.x;
  if (i >= n4) return;
  float4 v = ((const float4*)in)[i];
  ushort4 u;
  u.x = f2bf(v.x); u.y = f2bf(v.y); u.z = f2bf(v.z); u.w = f2bf(v.w);
  ((ushort4*)out)[i] = u;
}

// ---------------- DFT / iDFT matrices (bf16) ----------------
// CS: 256x128,  CS[k,n]=cos(2pi k n/128), CS[128+k,n]=-sin(2pi k n/128)
// W2: 128x256,  W2[n,k]=cos(2pi k n/128)/128, W2[n,128+k]=-sin(2pi k n/128)/128
__global__ __launch_bounds__(256) void init_mats(u16* __restrict__ CS, u16* __restrict__ W2) {
  int idx = blockIdx.x * 256 + threadIdx.x;  // [0, 32768)
  const float PI64 = 3.14159265358979323846f / 64.0f;
  {
    int j = idx >> 7, n = idx & 127;
    int k = j & 127;
    int t = (k * n) & 127;
    float ang = (float)t * PI64;
    float v = (j < 128) ? __cosf(ang) : -__sinf(ang);
    // use precise versions:
    v = (j < 128) ? cosf(ang) : -sinf(ang);
    CS[j * 128 + n] = f2bf(v);
  }
  {
    int n = idx >> 8, j = idx & 255;
    int k = j & 127;
    int t = (k * n) & 127;
    float ang = (float)t * PI64;
    float v = ((j < 128) ? cosf(ang) : -sinf(ang)) * (1.0f / 128.0f);
    W2[n * 256 + j] = f2bf(v);
  }
}

// ---------------- per-head L2 normalize, in place; scale = 1/sqrt(128*ss) ----------------
__global__ __launch_bounds__(256) void normalize_k(u16* __restrict__ q) {
  long vec = (long)blockIdx.x * 4 + (threadIdx.x >> 6);
  int lane = threadIdx.x & 63;
  u16* base = q + vec * 128;
  unsigned int u = *(const unsigned int*)(base + lane * 2);
  float a = bf2f((u16)(u & 0xffff));
  float b = bf2f((u16)(u >> 16));
  float ss = a * a + b * b;
#pragma unroll
  for (int m = 1; m < 64; m <<= 1) ss += __shfl_xor(ss, m);
  float scale = rsqrtf(ss * 128.0f);
  a *= scale; b *= scale;
  unsigned int w = (unsigned int)f2bf(a) | ((unsigned int)f2bf(b) << 16);
  *(unsigned int*)(base + lane * 2) = w;
}

// ---------------- scan over S (freq domain), chunked: NC=32 chunks of 128 ----------------
// KF rows: r = (b*4096 + t)*16 + h, 256 bf16 [re0..re127, im0..im127]
__global__ __launch_bounds__(256) void scan_chunksum(const u16* __restrict__ KF,
                                                     float* __restrict__ part) {
  int blk = blockIdx.x;          // (bh)*32 + c
  int c = blk & 31, bh = blk >> 5;
  int h = bh & 15, b = bh >> 4;
  int j = threadIdx.x;           // 0..255
  float s = 0.f;
  for (int t = c * 128; t < c * 128 + 128; ++t) {
    long r = ((long)(b * 4096 + t) * 16 + h) * 256;
    s += bf2f(KF[r + j]);
  }
  part[((long)bh * 32 + c) * 256 + j] = s;
}

__global__ __launch_bounds__(256) void scan_exclusive(float* __restrict__ part) {
  int bh = blockIdx.x;
  int j = threadIdx.x;
  float run = 0.f;
  for (int c = 0; c < 32; ++c) {
    long idx = ((long)bh * 32 + c) * 256 + j;
    float v = part[idx];
    part[idx] = run;
    run += v;
  }
}

// carries cumsum of KF and writes QV = QF * cum(KF) (complex), in place over KF buffer
__global__ __launch_bounds__(128) void scan_main(const u16* __restrict__ QF,
                                                 u16* KFQV,
                                                 const float* __restrict__ part) {
  int blk = blockIdx.x;
  int c = blk & 31, bh = blk >> 5;
  int h = bh & 15, b = bh >> 4;
  int k = threadIdx.x;  // 0..127
  float cr = part[((long)bh * 32 + c) * 256 + k];
  float ci = part[((long)bh * 32 + c) * 256 + 128 + k];
  for (int t = c * 128; t < c * 128 + 128; ++t) {
    long r = ((long)(b * 4096 + t) * 16 + h) * 256;
    float kfr = bf2f(KFQV[r + k]);
    float kfi = bf2f(KFQV[r + 128 + k]);
    float qfr = bf2f(QF[r + k]);
    float qfi = bf2f(QF[r + 128 + k]);
    cr += kfr; ci += kfi;
    float qvr = qfr * cr - qfi * ci;
    float qvi = qfr * ci + qfi * cr;
    KFQV[r + k] = f2bf(qvr);
    KFQV[r + 128 + k] = f2bf(qvi);
  }
}

extern "C" void kernel_launch(void* const* d_in, const int* in_sizes, int n_in,
                              void* d_out, int out_size, void* d_ws, size_t ws_size,
                              hipStream_t stream) {
  const float* x   = (const float*)d_in[0];
  const float* Wq  = (const float*)d_in[1];
  const float* Wkv = (const float*)d_in[2];
  const float* Wo  = (const float*)d_in[3];
  float* out = (float*)d_out;

  const long Bsz = 4, S = 4096, D = 2048, H = 16;
  const long M1 = Bsz * S;        // 16384
  const long R = M1 * H;          // 262144 head-rows
  const long XE = M1 * D;         // 33554432 elements
  const long WE = D * D;          // 4194304

  char* ws = (char*)d_ws;
  u16* QF   = (u16*)(ws);                         // R*256 bf16 = 134 MB
  u16* KF   = (u16*)(ws + 134217728);             // 134 MB (becomes QV in place)
  u16* xb   = (u16*)(ws + 268435456);             // 67 MB (later reused for V)
  u16* qh   = (u16*)(ws + 335544320);             // 67 MB
  u16* kh   = (u16*)(ws + 402653184);             // 67 MB
  u16* wqb  = (u16*)(ws + 469762048);             // 8.4 MB
  u16* wkb  = (u16*)(ws + 478150656);
  u16* wob  = (u16*)(ws + 486539264);
  u16* CS   = (u16*)(ws + 494927872);             // 64 KB
  u16* W2   = (u16*)(ws + 494993408);             // 64 KB
  float* part = (float*)(ws + 495058944);         // 2 MB
  u16* V = xb;                                    // alias: xb dead after GEMM2

  // casts
  cast_f2b<<<(int)(XE / 4 / 256), 256, 0, stream>>>(x, xb, (int)(XE / 4));
  cast_f2b<<<(int)(WE / 4 / 256), 256, 0, stream>>>(Wq, wqb, (int)(WE / 4));
  cast_f2b<<<(int)(WE / 4 / 256), 256, 0, stream>>>(Wkv, wkb, (int)(WE / 4));
  cast_f2b<<<(int)(WE / 4 / 256), 256, 0, stream>>>(Wo, wob, (int)(WE / 4));
  init_mats<<<128, 256, 0, stream>>>(CS, W2);

  // q = x @ Wq^T ; kv = x @ Wkv^T  (bf16 out)
  gemm_bt<true><<<(int)((M1 / 128) * (D / 128)), 256, 0, stream>>>(xb, wqb, qh, (int)M1, (int)D, (int)D);
  gemm_bt<true><<<(int)((M1 / 128) * (D / 128)), 256, 0, stream>>>(xb, wkb, kh, (int)M1, (int)D, (int)D);

  // per-head normalize (in place), scale = 1/sqrt(128*||v||^2)
  normalize_k<<<(int)(R / 4), 256, 0, stream>>>(qh);
  normalize_k<<<(int)(R / 4), 256, 0, stream>>>(kh);

  // DFT: QF = qh @ CS^T  (M=R, N=256, K=128)
  gemm_bt<true><<<(int)((R / 128) * 2), 256, 0, stream>>>(qh, CS, QF, (int)R, 256, 128);
  gemm_bt<true><<<(int)((R / 128) * 2), 256, 0, stream>>>(kh, CS, KF, (int)R, 256, 128);

  // chunked causal cumsum + complex multiply -> QV (in KF buffer)
  scan_chunksum<<<2048, 256, 0, stream>>>(KF, part);
  scan_exclusive<<<64, 256, 0, stream>>>(part);
  scan_main<<<2048, 128, 0, stream>>>(QF, KF, part);

  // iDFT: V = QV @ W2^T  (M=R, N=128, K=256)
  gemm_bt<true><<<(int)(R / 128), 256, 0, stream>>>(KF, W2, V, (int)R, 128, 256);

  // out = V @ Wo^T  (fp32 out), V viewed as (M1 x D)
  gemm_bt<false><<<(int)((M1 / 128) * (D / 128)), 256, 0, stream>>>(V, wob, out, (int)M1, (int)D, (int)D);
}

// Round 2
// 965.294 us; speedup vs baseline: 1.1064x; 1.1064x over previous
//
#include <hip/hip_runtime.h>
#include <hip/hip_bf16.h>

// HRR self-attention, real-arithmetic restructure (round 2):
//   qkv = x @ [Wq;Wkv]^T  (one bf16 MFMA GEMM, N=4096, per-head L2-normalize fused in epilogue)
//   F   = qkv_rows(2R x 128) @ CS^T  (DFT-128 as GEMM, out 2R x 256)
//   freq-domain causal cumsum of KF + complex mult -> QV (into dead qkv buffer)
//   V   = QV @ W2^T  (iDFT real part)
//   out = V @ Wo^T   (fp32 out)
// GEMMs use global_load_lds width-16 (m97 structure), unpadded LDS stride 32.

typedef unsigned short u16;
typedef unsigned int u32;
typedef __attribute__((ext_vector_type(8))) short short8;
typedef __attribute__((ext_vector_type(4))) float f32x4;

__device__ __forceinline__ float bf2f(u16 u) {
  u32 x = ((u32)u) << 16;
  float f; __builtin_memcpy(&f, &x, 4); return f;
}
__device__ __forceinline__ u16 f2bf(float f) {
  __hip_bfloat16 h = __float2bfloat16(f);
  u16 u; __builtin_memcpy(&u, &h, 2); return u;
}
__device__ __forceinline__ u32 pack2(float a, float b) {
  return (u32)f2bf(a) | ((u32)f2bf(b) << 16);
}

#define GLD16(gp, lp)                                                        \
  __builtin_amdgcn_global_load_lds(                                          \
      (const __attribute__((address_space(1))) void*)(gp),                   \
      (__attribute__((address_space(3))) void*)(lp), 16, 0, 0)

// ---------------- bf16 GEMM: C(MxN) = A(MxK) @ B(NxK)^T ----------------
// 128x128 tile, BK=32, 256 threads = 4 waves (2x2 of 64x64), mfma 16x16x32.
// EPI: 0 = fp32 out, 1 = bf16 out, 2 = bf16 out + per-128col-head normalize
//      (scale = 1/sqrt(128*rowblock_sumsq), Parseval-folded HRR normalize)
template <int EPI>
__global__ __launch_bounds__(256, 2) void gemm_bt(
    const u16* __restrict__ A, const u16* __restrict__ B, void* __restrict__ C,
    int M, int N, int K) {
  const int ntiles = N >> 7;
  const int bid = blockIdx.x;
  const int bm = bid / ntiles, bn = bid % ntiles;
  const long rowBase = (long)bm * 128, colBase = (long)bn * 128;

  __shared__ u16 As[128 * 32];  // unpadded: global_load_lds needs lane-contig dest
  __shared__ u16 Bs[128 * 32];
  __shared__ float ssbuf[128][2];

  const int tid = threadIdx.x;
  const int wave = tid >> 6, lane = tid & 63;
  const int quad = lane >> 4, l16 = lane & 15;
  const int waveRow = (wave >> 1) * 64, waveCol = (wave & 1) * 64;

  // staging: wave w stages As rows [w*32,w*32+32) and Bs rows likewise,
  // two 16-row segments each; lane i -> row i/4, cols (i&3)*8 (16B per lane)
  const int srow = lane >> 2, scol = (lane & 3) * 8;
  const u16* pa = A + (rowBase + wave * 32 + srow) * (long)K + scol;
  const u16* pb = B + (colBase + wave * 32 + srow) * (long)K + scol;
  u16* lA0 = &As[(wave * 32) * 32];
  u16* lA1 = &As[(wave * 32 + 16) * 32];
  u16* lB0 = &Bs[(wave * 32) * 32];
  u16* lB1 = &Bs[(wave * 32 + 16) * 32];

  f32x4 acc[4][4] = {};

  for (int kt = 0; kt < K; kt += 32) {
    GLD16(pa + kt, lA0);
    GLD16(pa + kt + 16 * (long)K, lA1);
    GLD16(pb + kt, lB0);
    GLD16(pb + kt + 16 * (long)K, lB1);
    __syncthreads();

    short8 af[4], bfr[4];
#pragma unroll
    for (int i = 0; i < 4; i++)
      af[i] = *(const short8*)&As[(waveRow + i * 16 + l16) * 32 + quad * 8];
#pragma unroll
    for (int j = 0; j < 4; j++)
      bfr[j] = *(const short8*)&Bs[(waveCol + j * 16 + l16) * 32 + quad * 8];
#pragma unroll
    for (int i = 0; i < 4; i++)
#pragma unroll
      for (int j = 0; j < 4; j++)
        acc[i][j] = __builtin_amdgcn_mfma_f32_16x16x32_bf16(af[i], bfr[j], acc[i][j], 0, 0, 0);
    __syncthreads();
  }

  float scl[4][4];
#pragma unroll
  for (int i = 0; i < 4; i++)
#pragma unroll
    for (int r = 0; r < 4; r++) scl[i][r] = 1.0f;

  if (EPI == 2) {
    // per-row sum of squares over this wave's 64 cols, then cross-wave via LDS
#pragma unroll
    for (int i = 0; i < 4; i++) {
#pragma unroll
      for (int r = 0; r < 4; r++) {
        float s = 0.f;
#pragma unroll
        for (int j = 0; j < 4; j++) { float v = acc[i][j][r]; s += v * v; }
#pragma unroll
        for (int m = 1; m < 16; m <<= 1) s += __shfl_xor(s, m);
        if (l16 == 0) ssbuf[waveRow + i * 16 + quad * 4 + r][wave & 1] = s;
      }
    }
    __syncthreads();
#pragma unroll
    for (int i = 0; i < 4; i++)
#pragma unroll
      for (int r = 0; r < 4; r++) {
        int row = waveRow + i * 16 + quad * 4 + r;
        scl[i][r] = rsqrtf(128.0f * (ssbuf[row][0] + ssbuf[row][1]));
      }
  }

  // C/D layout: col = lane&15, row = (lane>>4)*4 + reg  [verified m89/m91]
#pragma unroll
  for (int i = 0; i < 4; i++) {
#pragma unroll
    for (int j = 0; j < 4; j++) {
      long row0 = rowBase + waveRow + i * 16 + quad * 4;
      long col = colBase + waveCol + j * 16 + l16;
#pragma unroll
      for (int r = 0; r < 4; r++) {
        float v = acc[i][j][r] * scl[i][r];
        long off = (row0 + r) * (long)N + col;
        if (EPI == 0) ((float*)C)[off] = v;
        else          ((u16*)C)[off] = f2bf(v);
      }
    }
  }
}

// ---------------- fp32 -> bf16 cast (vectorized x4) ----------------
__global__ __launch_bounds__(256) void cast_f2b(const float* __restrict__ in,
                                                u16* __restrict__ out, int n4) {
  int i = blockIdx.x * 256 + threadIdx.x;
  if (i >= n4) return;
  float4 v = ((const float4*)in)[i];
  ushort4 u;
  u.x = f2bf(v.x); u.y = f2bf(v.y); u.z = f2bf(v.z); u.w = f2bf(v.w);
  ((ushort4*)out)[i] = u;
}

// ---------------- DFT / iDFT matrices (bf16) ----------------
// CS: 256x128,  CS[k,n]=cos(2pi k n/128), CS[128+k,n]=-sin(2pi k n/128)
// W2: 128x256,  W2[n,k]=cos(2pi k n/128)/128, W2[n,128+k]=-sin(2pi k n/128)/128
__global__ __launch_bounds__(256) void init_mats(u16* __restrict__ CS, u16* __restrict__ W2) {
  int idx = blockIdx.x * 256 + threadIdx.x;  // [0, 32768)
  const float PI64 = 3.14159265358979323846f / 64.0f;
  {
    int j = idx >> 7, n = idx & 127;
    int k = j & 127;
    int t = (k * n) & 127;
    float ang = (float)t * PI64;
    float v = (j < 128) ? cosf(ang) : -sinf(ang);
    CS[j * 128 + n] = f2bf(v);
  }
  {
    int n = idx >> 8, j = idx & 255;
    int k = j & 127;
    int t = (k * n) & 127;
    float ang = (float)t * PI64;
    float v = ((j < 128) ? cosf(ang) : -sinf(ang)) * (1.0f / 128.0f);
    W2[n * 256 + j] = f2bf(v);
  }
}

// ---------------- freq-domain causal cumsum (chunked scan) ----------------
// F rows: v = (b*4096+t)*32 + j; j<16 -> q head j, j>=16 -> kv head j-16.
// Each row: 256 bf16 [re0..re127, im0..im127].
__global__ __launch_bounds__(128) void scan_chunksum(const u16* __restrict__ F,
                                                     float* __restrict__ part) {
  int blk = blockIdx.x;          // bh*32 + c
  int c = blk & 31, bh = blk >> 5;
  int h = bh & 15, b = bh >> 4;
  int j = threadIdx.x;           // 0..127 -> bins 2j, 2j+1
  float s0 = 0.f, s1 = 0.f;
  for (int t = c * 128; t < c * 128 + 128; ++t) {
    long r = ((long)(b * 4096 + t) * 32 + 16 + h) * 256;
    u32 u = *(const u32*)&F[r + 2 * j];
    s0 += bf2f((u16)(u & 0xffff));
    s1 += bf2f((u16)(u >> 16));
  }
  long p = ((long)bh * 32 + c) * 256 + 2 * j;
  part[p] = s0; part[p + 1] = s1;
}

__global__ __launch_bounds__(256) void scan_exclusive(float* __restrict__ part) {
  int bh = blockIdx.x;
  int j = threadIdx.x;
  float run = 0.f;
  for (int c = 0; c < 32; ++c) {
    long idx = ((long)bh * 32 + c) * 256 + j;
    float v = part[idx];
    part[idx] = run;
    run += v;
  }
}

// carry cumsum of KF rows, QV = QF * cum(KF) (complex), write QV to dense R x 256
__global__ __launch_bounds__(64) void scan_main(const u16* __restrict__ F,
                                                u16* __restrict__ QV,
                                                const float* __restrict__ part) {
  int blk = blockIdx.x;
  int c = blk & 31, bh = blk >> 5;
  int h = bh & 15, b = bh >> 4;
  int k = threadIdx.x;  // 0..63 -> bins 2k, 2k+1
  long p = ((long)bh * 32 + c) * 256;
  float cr0 = part[p + 2 * k], cr1 = part[p + 2 * k + 1];
  float ci0 = part[p + 128 + 2 * k], ci1 = part[p + 128 + 2 * k + 1];
  for (int t = c * 128; t < c * 128 + 128; ++t) {
    long vb = ((long)(b * 4096 + t) * 32) * 256;
    u32 ur = *(const u32*)&F[vb + (16 + h) * 256 + 2 * k];
    u32 ui = *(const u32*)&F[vb + (16 + h) * 256 + 128 + 2 * k];
    u32 qr = *(const u32*)&F[vb + h * 256 + 2 * k];
    u32 qi = *(const u32*)&F[vb + h * 256 + 128 + 2 * k];
    cr0 += bf2f((u16)(ur & 0xffff)); cr1 += bf2f((u16)(ur >> 16));
    ci0 += bf2f((u16)(ui & 0xffff)); ci1 += bf2f((u16)(ui >> 16));
    float qr0 = bf2f((u16)(qr & 0xffff)), qr1 = bf2f((u16)(qr >> 16));
    float qi0 = bf2f((u16)(qi & 0xffff)), qi1 = bf2f((u16)(qi >> 16));
    float vr0 = qr0 * cr0 - qi0 * ci0, vr1 = qr1 * cr1 - qi1 * ci1;
    float vi0 = qr0 * ci0 + qi0 * cr0, vi1 = qr1 * ci1 + qi1 * cr1;
    long ob = ((long)(b * 4096 + t) * 16 + h) * 256;
    *(u32*)&QV[ob + 2 * k] = pack2(vr0, vr1);
    *(u32*)&QV[ob + 128 + 2 * k] = pack2(vi0, vi1);
  }
}

extern "C" void kernel_launch(void* const* d_in, const int* in_sizes, int n_in,
                              void* d_out, int out_size, void* d_ws, size_t ws_size,
                              hipStream_t stream) {
  const float* x   = (const float*)d_in[0];
  const float* Wq  = (const float*)d_in[1];
  const float* Wkv = (const float*)d_in[2];
  const float* Wo  = (const float*)d_in[3];
  float* out = (float*)d_out;

  const long M1 = 16384;          // B*S
  const long D = 2048;
  const long R = M1 * 16;         // 262144 head-rows
  const long XE = M1 * D;         // 33.5M elements
  const long WE = D * D;          // 4.19M

  char* ws = (char*)d_ws;
  u16* qkh  = (u16*)(ws);                         // 134 MB: GEMM1 out (16384x4096), later QV (R x 256)
  u16* F    = (u16*)(ws + 134217728);             // 268 MB: DFT out (2R x 256)
  u16* xb   = (u16*)(ws + 402653184);             // 67 MB: x bf16, later V (R x 128)
  u16* wqkb = (u16*)(ws + 469762048);             // 16.8 MB: [Wq;Wkv] bf16
  u16* wob  = (u16*)(ws + 486539264);             // 8.4 MB
  u16* CS   = (u16*)(ws + 494927872);             // 64 KB
  u16* W2   = (u16*)(ws + 494993408);             // 64 KB
  float* part = (float*)(ws + 495058944);         // 2 MB
  u16* V = xb;

  // casts (weights concatenated -> one N=4096 GEMM)
  cast_f2b<<<(int)(XE / 4 / 256), 256, 0, stream>>>(x, xb, (int)(XE / 4));
  cast_f2b<<<(int)(WE / 4 / 256), 256, 0, stream>>>(Wq, wqkb, (int)(WE / 4));
  cast_f2b<<<(int)(WE / 4 / 256), 256, 0, stream>>>(Wkv, wqkb + WE, (int)(WE / 4));
  cast_f2b<<<(int)(WE / 4 / 256), 256, 0, stream>>>(Wo, wob, (int)(WE / 4));
  init_mats<<<128, 256, 0, stream>>>(CS, W2);

  // qkv = x @ [Wq;Wkv]^T with fused per-head normalize (M=16384, N=4096, K=2048)
  gemm_bt<2><<<(int)((M1 / 128) * (4096 / 128)), 256, 0, stream>>>(
      xb, wqkb, qkh, (int)M1, 4096, (int)D);

  // DFT: F = qkv_rows @ CS^T  (M=2R, N=256, K=128)
  gemm_bt<1><<<(int)((2 * R / 128) * 2), 256, 0, stream>>>(
      qkh, CS, F, (int)(2 * R), 256, 128);

  // chunked causal cumsum + complex multiply -> QV (dense, into qkh)
  scan_chunksum<<<2048, 128, 0, stream>>>(F, part);
  scan_exclusive<<<64, 256, 0, stream>>>(part);
  scan_main<<<2048, 64, 0, stream>>>(F, qkh, part);

  // iDFT: V = QV @ W2^T  (M=R, N=128, K=256)
  gemm_bt<1><<<(int)(R / 128), 256, 0, stream>>>(qkh, W2, V, (int)R, 128, 256);

  // out = V @ Wo^T  (fp32 out, M=16384, N=2048, K=2048)
  gemm_bt<0><<<(int)((M1 / 128) * (D / 128)), 256, 0, stream>>>(
      V, wob, out, (int)M1, (int)D, (int)D);
}

// Round 3
// 822.790 us; speedup vs baseline: 1.2980x; 1.1732x over previous
//
#include <hip/hip_runtime.h>
#include <hip/hip_bf16.h>

// HRR self-attention, real-arithmetic + Hermitian-packed restructure (round 3):
//   qkv = x @ [Wq;Wkv]^T  (bf16 MFMA GEMM, per-head L2-normalize fused; Parseval)
//   F   = qkv_rows(2R x 128) @ CSp^T  (packed rDFT-128 as GEMM, out 2R x 128)
//         packed layout: slot 2k = re_k, slot 2k+1 = im_k (k=1..63), slot 1 = re_64
//   freq-domain causal cumsum of KF + complex mult -> QV (67 MB, packed)
//   out = QV_flat @ Wo2^T  where Wo2 = Wo (.) blockdiag-iDFT  (folded on device)
// GEMMs: m97 structure (global_load_lds width-16, unpadded LDS stride 32).

typedef unsigned short u16;
typedef unsigned int u32;
typedef __attribute__((ext_vector_type(8))) short short8;
typedef __attribute__((ext_vector_type(4))) float f32x4;

__device__ __forceinline__ float bf2f(u16 u) {
  u32 x = ((u32)u) << 16;
  float f; __builtin_memcpy(&f, &x, 4); return f;
}
__device__ __forceinline__ u16 f2bf(float f) {
  __hip_bfloat16 h = __float2bfloat16(f);
  u16 u; __builtin_memcpy(&u, &h, 2); return u;
}
__device__ __forceinline__ u32 pack2(float a, float b) {
  return (u32)f2bf(a) | ((u32)f2bf(b) << 16);
}

#define GLD16(gp, lp)                                                        \
  __builtin_amdgcn_global_load_lds(                                          \
      (const __attribute__((address_space(1))) void*)(gp),                   \
      (__attribute__((address_space(3))) void*)(lp), 16, 0, 0)

// ---------------- bf16 GEMM: C(MxN) = A(MxK) @ B(NxK)^T ----------------
// 128x128 tile, BK=32, 256 threads = 4 waves (2x2 of 64x64), mfma 16x16x32.
// EPI: 0 = fp32 out, 1 = bf16 out, 2 = bf16 + per-128col-head normalize
//      (scale = 1/sqrt(128*rowblock_sumsq), Parseval-folded HRR normalize)
// FOLD: A col-block selected by bn (block-diagonal right-multiply); B has 128
//       rows shared by all bn. lda = A row stride (=K when !FOLD).
template <int EPI, bool FOLD>
__global__ __launch_bounds__(256, 2) void gemm_bt(
    const u16* __restrict__ A, const u16* __restrict__ B, void* __restrict__ C,
    int M, int N, int K, int lda) {
  const int ntiles = N >> 7;
  const int bid = blockIdx.x;
  const int bm = bid / ntiles, bn = bid % ntiles;
  const long rowBase = (long)bm * 128, colBase = (long)bn * 128;
  const long aOff = FOLD ? colBase : 0;
  const long bRowBase = FOLD ? 0 : colBase;

  __shared__ u16 As[128 * 32];  // unpadded: global_load_lds needs lane-contig dest
  __shared__ u16 Bs[128 * 32];
  __shared__ float ssbuf[128][2];

  const int tid = threadIdx.x;
  const int wave = tid >> 6, lane = tid & 63;
  const int quad = lane >> 4, l16 = lane & 15;
  const int waveRow = (wave >> 1) * 64, waveCol = (wave & 1) * 64;

  // staging: wave w stages 32 rows of As/Bs; lane i -> row i/4, cols (i&3)*8
  const int srow = lane >> 2, scol = (lane & 3) * 8;
  const u16* pa = A + (rowBase + wave * 32 + srow) * (long)lda + aOff + scol;
  const u16* pb = B + (bRowBase + wave * 32 + srow) * (long)K + scol;
  u16* lA0 = &As[(wave * 32) * 32];
  u16* lA1 = &As[(wave * 32 + 16) * 32];
  u16* lB0 = &Bs[(wave * 32) * 32];
  u16* lB1 = &Bs[(wave * 32 + 16) * 32];

  f32x4 acc[4][4] = {};

  for (int kt = 0; kt < K; kt += 32) {
    GLD16(pa + kt, lA0);
    GLD16(pa + kt + 16 * (long)lda, lA1);
    GLD16(pb + kt, lB0);
    GLD16(pb + kt + 16 * (long)K, lB1);
    __syncthreads();

    short8 af[4], bfr[4];
#pragma unroll
    for (int i = 0; i < 4; i++)
      af[i] = *(const short8*)&As[(waveRow + i * 16 + l16) * 32 + quad * 8];
#pragma unroll
    for (int j = 0; j < 4; j++)
      bfr[j] = *(const short8*)&Bs[(waveCol + j * 16 + l16) * 32 + quad * 8];
#pragma unroll
    for (int i = 0; i < 4; i++)
#pragma unroll
      for (int j = 0; j < 4; j++)
        acc[i][j] = __builtin_amdgcn_mfma_f32_16x16x32_bf16(af[i], bfr[j], acc[i][j], 0, 0, 0);
    __syncthreads();
  }

  float scl[4][4];
#pragma unroll
  for (int i = 0; i < 4; i++)
#pragma unroll
    for (int r = 0; r < 4; r++) scl[i][r] = 1.0f;

  if (EPI == 2) {
#pragma unroll
    for (int i = 0; i < 4; i++) {
#pragma unroll
      for (int r = 0; r < 4; r++) {
        float s = 0.f;
#pragma unroll
        for (int j = 0; j < 4; j++) { float v = acc[i][j][r]; s += v * v; }
#pragma unroll
        for (int m = 1; m < 16; m <<= 1) s += __shfl_xor(s, m);
        if (l16 == 0) ssbuf[waveRow + i * 16 + quad * 4 + r][wave & 1] = s;
      }
    }
    __syncthreads();
#pragma unroll
    for (int i = 0; i < 4; i++)
#pragma unroll
      for (int r = 0; r < 4; r++) {
        int row = waveRow + i * 16 + quad * 4 + r;
        scl[i][r] = rsqrtf(128.0f * (ssbuf[row][0] + ssbuf[row][1]));
      }
  }

  // C/D layout: col = lane&15, row = (lane>>4)*4 + reg  [verified m89/m91]
#pragma unroll
  for (int i = 0; i < 4; i++) {
#pragma unroll
    for (int j = 0; j < 4; j++) {
      long row0 = rowBase + waveRow + i * 16 + quad * 4;
      long col = colBase + waveCol + j * 16 + l16;
#pragma unroll
      for (int r = 0; r < 4; r++) {
        float v = acc[i][j][r] * scl[i][r];
        long off = (row0 + r) * (long)N + col;
        if (EPI == 0) ((float*)C)[off] = v;
        else          ((u16*)C)[off] = f2bf(v);
      }
    }
  }
}

// ---------------- fp32 -> bf16 cast (vectorized x4) ----------------
__global__ __launch_bounds__(256) void cast_f2b(const float* __restrict__ in,
                                                u16* __restrict__ out, int n4) {
  int i = blockIdx.x * 256 + threadIdx.x;
  if (i >= n4) return;
  float4 v = ((const float4*)in)[i];
  ushort4 u;
  u.x = f2bf(v.x); u.y = f2bf(v.y); u.z = f2bf(v.z); u.w = f2bf(v.w);
  ((ushort4*)out)[i] = u;
}

// ---------------- packed-rDFT matrices (bf16) ----------------
// CSp (128x128), B-matrix of F = q @ CSp^T:
//   row p=2k   : cos(2pi k n/128)          (k=0..63)
//   row p=2k+1 : -sin(2pi k n/128)  (k>=1) ; row 1 : cos(pi n) = (-1)^n  (re_64)
// W2pT (128x128), B-matrix of fold Wo2_h = Wo_h @ W2p (C=A@B^T form, B[p,d]=W2p[d,p]):
//   p=0: 1/128 ; p=1: (-1)^d/128 ; p=2k: 2cos(2pi k d/128)/128 ; p=2k+1: -2sin(..)/128
__global__ __launch_bounds__(256) void init_mats(u16* __restrict__ CSp,
                                                 u16* __restrict__ W2pT) {
  int idx = blockIdx.x * 256 + threadIdx.x;  // [0, 32768)
  const float PI64 = 3.14159265358979323846f / 64.0f;
  if (idx < 16384) {
    int p = idx >> 7, n = idx & 127;
    int k = p >> 1;
    float v;
    if (p == 1) v = (n & 1) ? -1.f : 1.f;
    else {
      int t = (k * n) & 127;
      float ang = (float)t * PI64;
      v = (p & 1) ? -sinf(ang) : cosf(ang);
    }
    CSp[p * 128 + n] = f2bf(v);
  } else {
    int r = idx - 16384;
    int p = r >> 7, d = r & 127;
    int k = p >> 1;
    float v;
    if (p == 0) v = 1.0f / 128.0f;
    else if (p == 1) v = ((d & 1) ? -1.f : 1.f) / 128.0f;
    else {
      int t = (k * d) & 127;
      float ang = (float)t * PI64;
      v = ((p & 1) ? -2.f * sinf(ang) : 2.f * cosf(ang)) / 128.0f;
    }
    W2pT[p * 128 + d] = f2bf(v);
  }
}

// ---------------- freq-domain causal cumsum (chunked scan, packed rows) ----------------
// F rows: v = (b*4096+t)*32 + j; j<16 -> q head j, j>=16 -> kv head j-16.
// Row = 128 bf16 packed = 64 u32 bins; lane l owns bin l (l=0: two real bins).
// 64 chunks of 64 timesteps; bh = b*16+h in [0,64).
__global__ __launch_bounds__(64) void scan_chunksum(const u16* __restrict__ F,
                                                    float* __restrict__ part) {
  int blk = blockIdx.x;          // bh*64 + c
  int c = blk & 63, bh = blk >> 6;
  int h = bh & 15, b = bh >> 4;
  int l = threadIdx.x;           // 0..63
  float s0 = 0.f, s1 = 0.f;
  for (int t = c * 64; t < c * 64 + 64; ++t) {
    u32 u = ((const u32*)(F + ((long)(b * 4096 + t) * 32 + 16 + h) * 128))[l];
    s0 += bf2f((u16)(u & 0xffff));
    s1 += bf2f((u16)(u >> 16));
  }
  float2 w; w.x = s0; w.y = s1;
  ((float2*)part)[(long)blk * 64 + l] = w;
}

__global__ __launch_bounds__(128) void scan_exclusive(float* __restrict__ part) {
  int bh = blockIdx.x;   // 0..63
  int j = threadIdx.x;   // slot 0..127
  float run = 0.f;
  for (int c = 0; c < 64; ++c) {
    long idx = ((long)(bh * 64 + c)) * 128 + j;
    float v = part[idx];
    part[idx] = run;
    run += v;
  }
}

// carry cumsum of KF, QV = QF * cum(KF) (complex, packed), dense R x 128
__global__ __launch_bounds__(64) void scan_main(const u16* __restrict__ F,
                                                u16* __restrict__ QV,
                                                const float* __restrict__ part) {
  int blk = blockIdx.x;          // bh*64 + c
  int c = blk & 63, bh = blk >> 6;
  int h = bh & 15, b = bh >> 4;
  int l = threadIdx.x;           // bin l
  float2 cc = ((const float2*)part)[(long)blk * 64 + l];
  float cr = cc.x, ci = cc.y;
  for (int t = c * 64; t < c * 64 + 64; ++t) {
    long m = (long)(b * 4096 + t);
    u32 ku = ((const u32*)(F + (m * 32 + 16 + h) * 128))[l];
    u32 qu = ((const u32*)(F + (m * 32 + h) * 128))[l];
    float kr = bf2f((u16)(ku & 0xffff)), ki = bf2f((u16)(ku >> 16));
    float qr = bf2f((u16)(qu & 0xffff)), qi = bf2f((u16)(qu >> 16));
    cr += kr; ci += ki;
    float vr, vi;
    if (l == 0) { vr = qr * cr; vi = qi * ci; }  // bins 0 and 64: pure real
    else { vr = qr * cr - qi * ci; vi = qr * ci + qi * cr; }
    ((u32*)(QV + (m * 16 + h) * 128))[l] = pack2(vr, vi);
  }
}

extern "C" void kernel_launch(void* const* d_in, const int* in_sizes, int n_in,
                              void* d_out, int out_size, void* d_ws, size_t ws_size,
                              hipStream_t stream) {
  const float* x   = (const float*)d_in[0];
  const float* Wq  = (const float*)d_in[1];
  const float* Wkv = (const float*)d_in[2];
  const float* Wo  = (const float*)d_in[3];
  float* out = (float*)d_out;

  const long M1 = 16384;          // B*S
  const long D = 2048;
  const long R = M1 * 16;         // 262144 head-rows
  const long XE = M1 * D;
  const long WE = D * D;

  char* ws = (char*)d_ws;
  u16* qkh  = (u16*)(ws);                         // 134 MB: GEMM1 out (16384x4096); QV (Rx128, 67MB) reuses it
  u16* F    = (u16*)(ws + 134217728);             // 134 MB: packed DFT out (2R x 128)
  u16* xb   = (u16*)(ws + 268435456);             // 67 MB
  u16* wqkb = (u16*)(ws + 335544320);             // 16.8 MB: [Wq;Wkv]
  u16* wob  = (u16*)(ws + 352321536);             // 8.4 MB
  u16* wo2  = (u16*)(ws + 360710144);             // 8.4 MB: folded iDFT.Wo
  u16* CSp  = (u16*)(ws + 369098752);             // 32 KB
  u16* W2pT = (u16*)(ws + 369131520);             // 32 KB
  float* part = (float*)(ws + 369164288);         // 2 MB (64*64*128 f32)
  u16* QV = qkh;

  // casts + transform matrices
  cast_f2b<<<(int)(XE / 4 / 256), 256, 0, stream>>>(x, xb, (int)(XE / 4));
  cast_f2b<<<(int)(WE / 4 / 256), 256, 0, stream>>>(Wq, wqkb, (int)(WE / 4));
  cast_f2b<<<(int)(WE / 4 / 256), 256, 0, stream>>>(Wkv, wqkb + WE, (int)(WE / 4));
  cast_f2b<<<(int)(WE / 4 / 256), 256, 0, stream>>>(Wo, wob, (int)(WE / 4));
  init_mats<<<128, 256, 0, stream>>>(CSp, W2pT);

  // fold iDFT into Wo:  Wo2_h = Wo_h @ W2p  (block-diagonal, M=2048, N=2048, K=128)
  gemm_bt<1, true><<<16 * 16, 256, 0, stream>>>(wob, W2pT, wo2, 2048, 2048, 128, 2048);

  // qkv = x @ [Wq;Wkv]^T, fused per-head normalize (M=16384, N=4096, K=2048)
  gemm_bt<2, false><<<(int)((M1 / 128) * (4096 / 128)), 256, 0, stream>>>(
      xb, wqkb, qkh, (int)M1, 4096, (int)D, (int)D);

  // packed rDFT: F = qkv_rows @ CSp^T  (M=2R, N=128, K=128)
  gemm_bt<1, false><<<(int)(2 * R / 128), 256, 0, stream>>>(
      qkh, CSp, F, (int)(2 * R), 128, 128, 128);

  // chunked causal cumsum + complex multiply -> QV (packed, into qkh)
  scan_chunksum<<<64 * 64, 64, 0, stream>>>(F, part);
  scan_exclusive<<<64, 128, 0, stream>>>(part);
  scan_main<<<64 * 64, 64, 0, stream>>>(F, QV, part);

  // out = QV_flat @ Wo2^T  (fp32 out, M=16384, N=2048, K=2048; iDFT folded in)
  gemm_bt<0, false><<<(int)((M1 / 128) * (D / 128)), 256, 0, stream>>>(
      QV, wo2, out, (int)M1, (int)D, (int)D, (int)D);
}